// Round 10
// baseline (323.816 us; speedup 1.0000x reference)
//
#include <hip/hip_runtime.h>
#include <stdint.h>
#include <stddef.h>

#define N_NODES 8192
#define N_FEAT  512
#define EMB     128
#define N_HEADS 4
#define BT      128                     // block tile
#define TG      (N_NODES / BT)          // 64
#define NPAIR   (TG * (TG + 1) / 2)     // 2080 (divisible by 8)

typedef __attribute__((ext_vector_type(8))) short bf16x8;
typedef __attribute__((ext_vector_type(4))) float f32x4;

__device__ __forceinline__ unsigned short f2bf(float f) {
  union { float f; unsigned int u; } x; x.f = f;
  unsigned int r = (x.u + 0x7FFFu + ((x.u >> 16) & 1u)) >> 16;
  return (unsigned short)r;
}
__device__ __forceinline__ float bf2f(unsigned short u) {
  union { unsigned int u; float f; } x; x.u = ((unsigned int)u) << 16;
  return x.f;
}

// async global->LDS, 16B/lane; LDS dest wave-uniform base (HW adds lane*16)
__device__ __forceinline__ void gl_lds16(const unsigned short* g, unsigned short* l) {
  __builtin_amdgcn_global_load_lds(
      (__attribute__((address_space(1))) void*)(void*)g,
      (__attribute__((address_space(3))) void*)l, 16, 0, 0);
}

// frag-linear-16 (16-col groups) flat index (shorts), for 16x16x32 B-frags:
// [g=n>>4][kk=k>>5][lane=((k>>3)&3)<<4 | (n&15)][e=k&7]
__device__ __forceinline__ size_t frag16(int n, int k) {
  return ((size_t)((n >> 4) * 4 + (k >> 5)) * 64
          + ((((k >> 3) & 3) << 4) | (n & 15))) * 8 + (k & 7);
}

// bf16 [128][128] transpose/park buffer index
__device__ __forceinline__ int tix(int r, int c) {
  return r * 128 + (c ^ (r & 31));
}

// ---------- kernel 1: X_emb = X@W, row-normalize, bf16, frag16 write ----------
__global__ void __launch_bounds__(512) xw_kernel(const float* __restrict__ X,
                                                 const float* __restrict__ W,
                                                 unsigned short* __restrict__ Xf) {
  __shared__ float xs[32][N_FEAT];    // 64KB
  const int t = threadIdx.x;
  const int row0 = blockIdx.x * 32;
#pragma unroll
  for (int i = 0; i < 8; ++i) {
    int e4 = i * 512 + t;
    int row = e4 >> 7;
    int col = (e4 & 127) * 4;
    *(float4*)&xs[row][col] = *(const float4*)&X[(size_t)(row0 + row) * N_FEAT + col];
  }
  __syncthreads();
  const int c0 = (t & 31) * 4;
  const int r0 = (t >> 5) * 2;
  float a00=0.f,a01=0.f,a02=0.f,a03=0.f,a10=0.f,a11=0.f,a12=0.f,a13=0.f;
  for (int k = 0; k < N_FEAT; k += 2) {
    float4 w0 = *(const float4*)&W[(size_t)k * EMB + c0];
    float4 w1 = *(const float4*)&W[(size_t)(k + 1) * EMB + c0];
    float x00 = xs[r0][k],     x01 = xs[r0][k + 1];
    float x10 = xs[r0 + 1][k], x11 = xs[r0 + 1][k + 1];
    a00 += x00*w0.x; a01 += x00*w0.y; a02 += x00*w0.z; a03 += x00*w0.w;
    a10 += x10*w0.x; a11 += x10*w0.y; a12 += x10*w0.z; a13 += x10*w0.w;
    a00 += x01*w1.x; a01 += x01*w1.y; a02 += x01*w1.z; a03 += x01*w1.w;
    a10 += x11*w1.x; a11 += x11*w1.y; a12 += x11*w1.z; a13 += x11*w1.w;
  }
  float s0 = a00*a00 + a01*a01 + a02*a02 + a03*a03;
  float s1 = a10*a10 + a11*a11 + a12*a12 + a13*a13;
#pragma unroll
  for (int off = 16; off >= 1; off >>= 1) {
    s0 += __shfl_xor(s0, off);
    s1 += __shfl_xor(s1, off);
  }
  float inv0 = 1.0f / (sqrtf(s0) + 1e-6f);
  float inv1 = 1.0f / (sqrtf(s1) + 1e-6f);
  union { unsigned short u[4]; uint2 v; } o0, o1;
  o0.u[0]=f2bf(a00*inv0); o0.u[1]=f2bf(a01*inv0); o0.u[2]=f2bf(a02*inv0); o0.u[3]=f2bf(a03*inv0);
  o1.u[0]=f2bf(a10*inv1); o1.u[1]=f2bf(a11*inv1); o1.u[2]=f2bf(a12*inv1); o1.u[3]=f2bf(a13*inv1);
  int n0 = row0 + r0;
  *(uint2*)&Xf[frag16(n0, c0)] = o0.v;        // c0&7 in {0,4}: 8B aligned ✓
  *(uint2*)&Xf[frag16(n0 + 1, c0)] = o1.v;
}

// ---------- kernel 2: Z row-normalize + bf16, frag16 write ----------
__global__ void __launch_bounds__(256) znorm_kernel(const float* __restrict__ in,
                                                    unsigned short* __restrict__ Zf) {
  const int row = blockIdx.x * 4 + (threadIdx.x >> 6);
  const int lane = threadIdx.x & 63;
  float2 v = *(const float2*)&in[(size_t)row * EMB + lane * 2];
  float ss = v.x * v.x + v.y * v.y;
#pragma unroll
  for (int off = 32; off >= 1; off >>= 1) ss += __shfl_xor(ss, off);
  const float s = 1.0f / (sqrtf(ss) + 1e-6f);
  union { unsigned short u[2]; unsigned int w; } o;
  o.u[0] = f2bf(v.x * s);
  o.u[1] = f2bf(v.y * s);
  const int h = row >> 13;
  const int n = row & 8191;
  const int c = lane * 2;                      // c&7 even: 4B aligned ✓
  *(unsigned int*)&Zf[((size_t)h << 20) + frag16(n, c)] = o.w;
}

// ---------- kernel 3: fused affinity — LDS-pipelined A, register-held B ----------
// stage one [128 rows][32 k] A-slice (8KB) from a frag16 tile base into linear LDS
__device__ __forceinline__ void stageA(unsigned short* dst,
                                       const unsigned short* __restrict__ src16,
                                       int ks, int w, int lane) {
#pragma unroll
  for (int i = 0; i < 2; ++i) {
    int slot = w * 128 + i * 64 + lane;        // 0..511; row=slot>>2, cq=slot&3
    int row = slot >> 2, cq = slot & 3;
    const unsigned short* g = src16 + ((size_t)((row >> 4) * 4 + ks)) * 512
                              + (((cq << 4) | (row & 15)) * 8);
    gl_lds16(g, dst + (size_t)(w * 128 + i * 64) * 8);
  }
}

__global__ void __launch_bounds__(256)
affinity_kernel(const unsigned short* __restrict__ Xf,
                const unsigned short* __restrict__ Zf,
                const float* __restrict__ betap,
                float* __restrict__ out) {
  __shared__ __align__(16) unsigned short Asl[2][128 * 32];  // 2x8KB A dbuf
  __shared__ unsigned short Tb[BT * BT];                     // 32KB park/transpose

  // XCD-bijective swizzle (2080 % 8 == 0)
  int bid = blockIdx.x;
  int p = (bid & 7) * (NPAIR / 8) + (bid >> 3);
  // panel decode: 4x4 super-grid of 16x16 tiles over the (bi<=bj) triangle
  int bi, bj;
  {
    int rem = p, Bi = 0, Bj = 0;
    for (Bi = 0; Bi < 4; ++Bi) {
      bool done = false;
      for (Bj = Bi; Bj < 4; ++Bj) {
        int cnt = (Bi == Bj) ? 136 : 256;
        if (rem < cnt) { done = true; break; }
        rem -= cnt;
      }
      if (done) break;
    }
    int li, lj;
    if (Bi == Bj) {
      li = 0;
      while (rem >= 16 - li) { rem -= 16 - li; ++li; }
      lj = li + rem;
    } else {
      li = rem >> 4;
      lj = rem & 15;
    }
    bi = Bi * 16 + li;
    bj = Bj * 16 + lj;
  }
  const bool diag = (bi == bj);

  const int t = threadIdx.x;
  const int lane = t & 63;
  const int w = t >> 6;               // 4 waves: 2x2 of 64x64
  const int R0 = (w >> 1) * 64;
  const int C0 = (w & 1) * 64;
  const int fcol = lane & 15;         // fragment col / A-row low
  const int fkq = lane >> 4;          // fragment k-quarter

  const size_t HS = (size_t)1 << 20;  // Zf head stride (shorts)
  const unsigned short* ZIbase = Zf + (size_t)(bi * 8) * 2048;  // frag16 tile base (A, phase I)
  const unsigned short* XIbase = Xf + (size_t)(bi * 8) * 2048;  // frag16 tile base (A, phase J)
  const unsigned short* BJbase = Xf + (size_t)(bj * 8 + (C0 >> 4)) * 2048;  // B phase I
  const unsigned short* BZbase = Zf + (size_t)(bj * 8 + (C0 >> 4)) * 2048;  // B phase J (+h*HS)

  bf16x8 B[4][4];                     // [ks][ct] held B fragments (64 VGPR)
  f32x4 acc[4][4], m[4][4];           // working + running max (128 VGPR)

  // ---------------- phase I: maxI = max_h Z[h][bi-rows] . Xe[bj-cols] ----------------
#pragma unroll
  for (int ks = 0; ks < 4; ++ks)
#pragma unroll
    for (int ct = 0; ct < 4; ++ct)
      B[ks][ct] = *(const bf16x8*)&BJbase[(size_t)ct * 2048 + ks * 512 + lane * 8];

#pragma unroll
  for (int rt = 0; rt < 4; ++rt)
#pragma unroll
    for (int ct = 0; ct < 4; ++ct) {
      acc[rt][ct] = (f32x4){0.f, 0.f, 0.f, 0.f};
      m[rt][ct] = (f32x4){-3.0e38f, -3.0e38f, -3.0e38f, -3.0e38f};
    }

  stageA(Asl[0], ZIbase, 0, w, lane);   // (h0, ks0)
  __syncthreads();

#pragma unroll
  for (int h = 0; h < N_HEADS; ++h) {
#pragma unroll
    for (int ks = 0; ks < 4; ++ks) {
      const int s = h * 4 + ks;
      const int cur = s & 1;
      if (s < 15) {
        const int ns = s + 1;
        stageA(Asl[ns & 1], ZIbase + (size_t)(ns >> 2) * HS, ns & 3, w, lane);
      } else if (!diag) {
        stageA(Asl[(s + 1) & 1], XIbase, 0, w, lane);   // prefetch phase J ks0
      }
      // A-frags from linear LDS (bank-optimal) + MFMA
      bf16x8 a[4];
#pragma unroll
      for (int rt = 0; rt < 4; ++rt)
        a[rt] = *(const bf16x8*)&Asl[cur][(R0 + rt * 16 + fcol) * 32 + (fkq << 3)];
#pragma unroll
      for (int rt = 0; rt < 4; ++rt)
#pragma unroll
        for (int ct = 0; ct < 4; ++ct)
          acc[rt][ct] = __builtin_amdgcn_mfma_f32_16x16x32_bf16(a[rt], B[ks][ct],
                                                                acc[rt][ct], 0, 0, 0);
      if (ks == 3) {
#pragma unroll
        for (int rt = 0; rt < 4; ++rt)
#pragma unroll
          for (int ct = 0; ct < 4; ++ct)
#pragma unroll
            for (int q = 0; q < 4; ++q) {
              m[rt][ct][q] = fmaxf(m[rt][ct][q], acc[rt][ct][q]);
              acc[rt][ct][q] = 0.f;
            }
      }
      __syncthreads();
    }
  }

  // park maxI (bf16) in Tb at natural (r,c) — thread-private slots
#pragma unroll
  for (int rt = 0; rt < 4; ++rt)
#pragma unroll
    for (int ct = 0; ct < 4; ++ct)
#pragma unroll
      for (int q = 0; q < 4; ++q) {
        int r = R0 + rt * 16 + fkq * 4 + q;
        int c = C0 + ct * 16 + fcol;
        Tb[tix(r, c)] = f2bf(m[rt][ct][q]);
      }

  const float beta = betap[0];
  const bool bp = (beta != 1.0f);

  if (diag) {
    __syncthreads();
#pragma unroll
    for (int rt = 0; rt < 4; ++rt)
#pragma unroll
      for (int ct = 0; ct < 4; ++ct)
#pragma unroll
        for (int q = 0; q < 4; ++q) {
          int r = R0 + rt * 16 + fkq * 4 + q;
          int c = C0 + ct * 16 + fcol;
          float v = 0.25f * (m[rt][ct][q] + bf2f(Tb[tix(c, r)])) + 0.5f;
          if (bp) v = powf(v, beta);
          out[(size_t)(bi * BT + r) * N_NODES + (size_t)(bi * BT + c)] = v;
        }
    return;
  }

  // ---------------- phase J: maxJT = max_h Xe[bi-rows] . Z[h][bj-cols] ----------------
#pragma unroll
  for (int rt = 0; rt < 4; ++rt)
#pragma unroll
    for (int ct = 0; ct < 4; ++ct)
      m[rt][ct] = (f32x4){-3.0e38f, -3.0e38f, -3.0e38f, -3.0e38f};

#pragma unroll
  for (int h = 0; h < N_HEADS; ++h) {
    // B = Z[h][bj-cols], all 4 k-slices
#pragma unroll
    for (int ks = 0; ks < 4; ++ks)
#pragma unroll
      for (int ct = 0; ct < 4; ++ct)
        B[ks][ct] = *(const bf16x8*)&BZbase[(size_t)h * HS + (size_t)ct * 2048
                                            + ks * 512 + lane * 8];
#pragma unroll
    for (int ks = 0; ks < 4; ++ks) {
      const int s = h * 4 + ks;
      const int cur = s & 1;
      if (s < 15) {
        stageA(Asl[(s + 1) & 1], XIbase, (s + 1) & 3, w, lane);  // A = X, h-independent
      }
      bf16x8 a[4];
#pragma unroll
      for (int rt = 0; rt < 4; ++rt)
        a[rt] = *(const bf16x8*)&Asl[cur][(R0 + rt * 16 + fcol) * 32 + (fkq << 3)];
#pragma unroll
      for (int rt = 0; rt < 4; ++rt)
#pragma unroll
        for (int ct = 0; ct < 4; ++ct)
          acc[rt][ct] = __builtin_amdgcn_mfma_f32_16x16x32_bf16(a[rt], B[ks][ct],
                                                                acc[rt][ct], 0, 0, 0);
      if (ks == 3) {
#pragma unroll
        for (int rt = 0; rt < 4; ++rt)
#pragma unroll
          for (int ct = 0; ct < 4; ++ct)
#pragma unroll
            for (int q = 0; q < 4; ++q) {
              m[rt][ct][q] = fmaxf(m[rt][ct][q], acc[rt][ct][q]);
              acc[rt][ct][q] = 0.f;
            }
      }
      __syncthreads();
    }
  }

  // ---------------- epilogue ----------------
  float vv[4][4][4];
#pragma unroll
  for (int rt = 0; rt < 4; ++rt)
#pragma unroll
    for (int ct = 0; ct < 4; ++ct)
#pragma unroll
      for (int q = 0; q < 4; ++q) {
        int r = R0 + rt * 16 + fkq * 4 + q;
        int c = C0 + ct * 16 + fcol;
        float a = bf2f(Tb[tix(r, c)]);          // maxI (own slot)
        float v = 0.25f * (a + m[rt][ct][q]) + 0.5f;
        if (bp) v = powf(v, beta);
        out[(size_t)(bi * BT + r) * N_NODES + (size_t)(bj * BT + c)] = v;
        vv[rt][ct][q] = v;
      }

  __syncthreads();
#pragma unroll
  for (int rt = 0; rt < 4; ++rt)
#pragma unroll
    for (int ct = 0; ct < 4; ++ct)
#pragma unroll
      for (int q = 0; q < 4; ++q) {
        int r = R0 + rt * 16 + fkq * 4 + q;
        int c = C0 + ct * 16 + fcol;
        Tb[tix(c, r)] = f2bf(vv[rt][ct][q]);    // park v transposed
      }
  __syncthreads();
#pragma unroll
  for (int it = 0; it < 64; ++it) {
    int row = it * 2 + (t >> 7);
    int col = t & 127;
    out[(size_t)(bj * BT + row) * N_NODES + (size_t)(bi * BT + col)] =
        bf2f(Tb[tix(row, col)]);
  }
}

extern "C" void kernel_launch(void* const* d_in, const int* in_sizes, int n_in,
                              void* d_out, int out_size, void* d_ws, size_t ws_size,
                              hipStream_t stream) {
  const float* X = (const float*)d_in[0];
  const float* W = (const float*)d_in[1];
  const float* Z = (const float*)d_in[2];
  const float* beta = (const float*)d_in[3];
  float* out = (float*)d_out;
  char* ws = (char*)d_ws;

  unsigned short* Xf = (unsigned short*)ws;                // 2 MiB frag16 bf16
  unsigned short* Zf = (unsigned short*)(ws + (2u << 20)); // 8 MiB frag16 bf16

  hipLaunchKernelGGL(xw_kernel, dim3(N_NODES / 32), dim3(512), 0, stream, X, W, Xf);
  hipLaunchKernelGGL(znorm_kernel, dim3(N_HEADS * N_NODES / 4), dim3(256), 0, stream, Z, Zf);
  hipLaunchKernelGGL(affinity_kernel, dim3(NPAIR), dim3(256), 0, stream, Xf, Zf, beta, out);
}

// Round 11
// 229.674 us; speedup vs baseline: 1.4099x; 1.4099x over previous
//
#include <hip/hip_runtime.h>
#include <stdint.h>
#include <stddef.h>

#define N_NODES 8192
#define N_FEAT  512
#define EMB     128
#define N_HEADS 4
#define BT      128                     // block tile
#define TG      (N_NODES / BT)          // 64
#define NPAIR   (TG * (TG + 1) / 2)     // 2080 (divisible by 8)

typedef __attribute__((ext_vector_type(8))) short bf16x8;
typedef __attribute__((ext_vector_type(4))) float f32x4;

__device__ __forceinline__ unsigned short f2bf(float f) {
  union { float f; unsigned int u; } x; x.f = f;
  unsigned int r = (x.u + 0x7FFFu + ((x.u >> 16) & 1u)) >> 16;
  return (unsigned short)r;
}
__device__ __forceinline__ float bf2f(unsigned short u) {
  union { unsigned int u; float f; } x; x.u = ((unsigned int)u) << 16;
  return x.f;
}

// async global->LDS, 16B/lane; LDS dest wave-uniform base (HW adds lane*16)
__device__ __forceinline__ void gl_lds16(const unsigned short* g, unsigned short* l) {
  __builtin_amdgcn_global_load_lds(
      (__attribute__((address_space(1))) void*)(void*)g,
      (__attribute__((address_space(3))) void*)l, 16, 0, 0);
}

// K-sliced layout (shorts): [tile=n>>7][ks=k>>5][row=n&127][k&31]
__device__ __forceinline__ size_t ksl(int n, int k) {
  return ((size_t)((n >> 7) * 4 + (k >> 5)) * 128 + (n & 127)) * 32 + (k & 31);
}

// ---------- kernel 1: X_emb = X@W, row-normalize, bf16, K-sliced write ----------
__global__ void __launch_bounds__(512) xw_kernel(const float* __restrict__ X,
                                                 const float* __restrict__ W,
                                                 unsigned short* __restrict__ Xs) {
  __shared__ float xs[32][N_FEAT];    // 64KB
  const int t = threadIdx.x;
  const int row0 = blockIdx.x * 32;
#pragma unroll
  for (int i = 0; i < 8; ++i) {
    int e4 = i * 512 + t;
    int row = e4 >> 7;
    int col = (e4 & 127) * 4;
    *(float4*)&xs[row][col] = *(const float4*)&X[(size_t)(row0 + row) * N_FEAT + col];
  }
  __syncthreads();
  const int c0 = (t & 31) * 4;
  const int r0 = (t >> 5) * 2;
  float a00=0.f,a01=0.f,a02=0.f,a03=0.f,a10=0.f,a11=0.f,a12=0.f,a13=0.f;
  for (int k = 0; k < N_FEAT; k += 2) {
    float4 w0 = *(const float4*)&W[(size_t)k * EMB + c0];
    float4 w1 = *(const float4*)&W[(size_t)(k + 1) * EMB + c0];
    float x00 = xs[r0][k],     x01 = xs[r0][k + 1];
    float x10 = xs[r0 + 1][k], x11 = xs[r0 + 1][k + 1];
    a00 += x00*w0.x; a01 += x00*w0.y; a02 += x00*w0.z; a03 += x00*w0.w;
    a10 += x10*w0.x; a11 += x10*w0.y; a12 += x10*w0.z; a13 += x10*w0.w;
    a00 += x01*w1.x; a01 += x01*w1.y; a02 += x01*w1.z; a03 += x01*w1.w;
    a10 += x11*w1.x; a11 += x11*w1.y; a12 += x11*w1.z; a13 += x11*w1.w;
  }
  float s0 = a00*a00 + a01*a01 + a02*a02 + a03*a03;
  float s1 = a10*a10 + a11*a11 + a12*a12 + a13*a13;
#pragma unroll
  for (int off = 16; off >= 1; off >>= 1) {
    s0 += __shfl_xor(s0, off);
    s1 += __shfl_xor(s1, off);
  }
  float inv0 = 1.0f / (sqrtf(s0) + 1e-6f);
  float inv1 = 1.0f / (sqrtf(s1) + 1e-6f);
  union { unsigned short u[4]; uint2 v; } o0, o1;
  o0.u[0]=f2bf(a00*inv0); o0.u[1]=f2bf(a01*inv0); o0.u[2]=f2bf(a02*inv0); o0.u[3]=f2bf(a03*inv0);
  o1.u[0]=f2bf(a10*inv1); o1.u[1]=f2bf(a11*inv1); o1.u[2]=f2bf(a12*inv1); o1.u[3]=f2bf(a13*inv1);
  int n0 = row0 + r0;
  *(uint2*)&Xs[ksl(n0, c0)] = o0.v;          // (c0&31)*2B in {0,8,..}: 8B aligned
  *(uint2*)&Xs[ksl(n0 + 1, c0)] = o1.v;
}

// ---------- kernel 2: Z row-normalize + bf16, K-sliced write ----------
__global__ void __launch_bounds__(256) znorm_kernel(const float* __restrict__ in,
                                                    unsigned short* __restrict__ Zs) {
  const int row = blockIdx.x * 4 + (threadIdx.x >> 6);
  const int lane = threadIdx.x & 63;
  float2 v = *(const float2*)&in[(size_t)row * EMB + lane * 2];
  float ss = v.x * v.x + v.y * v.y;
#pragma unroll
  for (int off = 32; off >= 1; off >>= 1) ss += __shfl_xor(ss, off);
  const float s = 1.0f / (sqrtf(ss) + 1e-6f);
  union { unsigned short u[2]; unsigned int w; } o;
  o.u[0] = f2bf(v.x * s);
  o.u[1] = f2bf(v.y * s);
  const int h = row >> 13;
  const int n = row & 8191;
  const int c = lane * 2;
  *(unsigned int*)&Zs[((size_t)h << 20) + ksl(n, c)] = o.w;   // 4B aligned
}

// ---------- kernel 3: fused affinity — m97-style LDS pipeline ----------
__global__ void __launch_bounds__(512, 4)
affinity_kernel(const unsigned short* __restrict__ Xs,
                const unsigned short* __restrict__ Zs,
                const float* __restrict__ betap,
                float* __restrict__ out) {
  __shared__ __align__(16) unsigned short Fixed[4 * 4096];   // 32KB: 4 K-slices, held operand
  __shared__ __align__(16) unsigned short Stream[2][4096];   // 16KB: streamed-operand dbuf
  __shared__ __align__(16) unsigned int Park[8192];          // 32KB: mI park, then bf16 Tb
  unsigned short* Tb = (unsigned short*)Park;

  // XCD-bijective swizzle + panel decode (R9)
  int bid = blockIdx.x;
  int p = (bid & 7) * (NPAIR / 8) + (bid >> 3);
  int bi, bj;
  {
    int rem = p, Bi = 0, Bj = 0;
    for (Bi = 0; Bi < 4; ++Bi) {
      bool done = false;
      for (Bj = Bi; Bj < 4; ++Bj) {
        int cnt = (Bi == Bj) ? 136 : 256;
        if (rem < cnt) { done = true; break; }
        rem -= cnt;
      }
      if (done) break;
    }
    int li, lj;
    if (Bi == Bj) {
      li = 0;
      while (rem >= 16 - li) { rem -= 16 - li; ++li; }
      lj = li + rem;
    } else {
      li = rem >> 4;
      lj = rem & 15;
    }
    bi = Bi * 16 + li;
    bj = Bj * 16 + lj;
  }

  const int t = threadIdx.x;
  const int lane = t & 63;
  const int w = t >> 6;                // 8 waves: 2 row-groups x 4 col-groups
  const int R0 = (w >> 2) * 64;        // 64 rows per group (4 x 16)
  const int C0 = (w & 3) * 32;         // 32 cols per group (2 x 16)
  const int fcol = lane & 15;
  const int fkq = lane >> 4;
  const int soff = (w * 64 + lane) * 8;   // staging source offset (shorts)
  const int sdst = w * 512;               // staging LDS offset (shorts), wave-uniform
  const int fro = fkq * 8;                // frag k-offset (shorts)

  const unsigned short* Xbj = Xs + ((size_t)(bj * 4) << 12);
  const unsigned short* Xbi = Xs + ((size_t)(bi * 4) << 12);

  f32x4 acc[4][2], m[4][2];
#pragma unroll
  for (int rt = 0; rt < 4; ++rt)
#pragma unroll
    for (int ct = 0; ct < 2; ++ct) {
      acc[rt][ct] = (f32x4){0.f, 0.f, 0.f, 0.f};
      m[rt][ct] = (f32x4){-3.0e38f, -3.0e38f, -3.0e38f, -3.0e38f};
    }

  // prologue: Fixed <- X_bj (4 slices), Stream[0] <- Z[h0][bi][ks0]
#pragma unroll
  for (int f = 0; f < 4; ++f)
    gl_lds16(Xbj + (f << 12) + soff, Fixed + f * 4096 + sdst);
  gl_lds16(Zs + (((size_t)(bi * 4)) << 12) + soff, Stream[0] + sdst);
  __syncthreads();

  // ---- phase I: mI = max_h Z[h][bi-rows] . Xe[bj-cols] ----
#pragma unroll
  for (int s = 0; s < 16; ++s) {
    if (s < 15) {
      const int ns = s + 1;
      gl_lds16(Zs + (((size_t)(((ns >> 2) * 64 + bi) * 4 + (ns & 3))) << 12) + soff,
               Stream[ns & 1] + sdst);
    }
    const unsigned short* As = Stream[s & 1];
    const unsigned short* Bs = Fixed + (s & 3) * 4096;
    bf16x8 b0 = *(const bf16x8*)&Bs[(C0 + fcol) * 32 + fro];
    bf16x8 b1 = *(const bf16x8*)&Bs[(C0 + 16 + fcol) * 32 + fro];
#pragma unroll
    for (int rt = 0; rt < 4; ++rt) {
      bf16x8 a = *(const bf16x8*)&As[(R0 + rt * 16 + fcol) * 32 + fro];
      acc[rt][0] = __builtin_amdgcn_mfma_f32_16x16x32_bf16(a, b0, acc[rt][0], 0, 0, 0);
      acc[rt][1] = __builtin_amdgcn_mfma_f32_16x16x32_bf16(a, b1, acc[rt][1], 0, 0, 0);
    }
    if ((s & 3) == 3) {
#pragma unroll
      for (int rt = 0; rt < 4; ++rt)
#pragma unroll
        for (int ct = 0; ct < 2; ++ct)
#pragma unroll
          for (int q = 0; q < 4; ++q) {
            m[rt][ct][q] = fmaxf(m[rt][ct][q], acc[rt][ct][q]);
            acc[rt][ct][q] = 0.f;
          }
    }
    __syncthreads();
  }

  // ---- boundary: restage Fixed <- X_bi, Stream[0] <- Z[h0][bj][ks0]; park mI ----
#pragma unroll
  for (int f = 0; f < 4; ++f)
    gl_lds16(Xbi + (f << 12) + soff, Fixed + f * 4096 + sdst);
  gl_lds16(Zs + (((size_t)(bj * 4)) << 12) + soff, Stream[0] + sdst);
#pragma unroll
  for (int rt = 0; rt < 4; ++rt)
#pragma unroll
    for (int ct = 0; ct < 2; ++ct)
#pragma unroll
      for (int pp = 0; pp < 2; ++pp) {
        unsigned int pk = (unsigned int)f2bf(m[rt][ct][pp * 2]) |
                          ((unsigned int)f2bf(m[rt][ct][pp * 2 + 1]) << 16);
        Park[(((rt * 2 + ct) * 2 + pp) * 512) + t] = pk;   // lane-consecutive: 0-conflict
      }
#pragma unroll
  for (int rt = 0; rt < 4; ++rt)
#pragma unroll
    for (int ct = 0; ct < 2; ++ct)
      m[rt][ct] = (f32x4){-3.0e38f, -3.0e38f, -3.0e38f, -3.0e38f};
  __syncthreads();

  // ---- phase J (swapped operands): mJT = max_h Xe[bi-rows] . Z[h][bj-cols] ----
#pragma unroll
  for (int s = 0; s < 16; ++s) {
    if (s < 15) {
      const int ns = s + 1;
      gl_lds16(Zs + (((size_t)(((ns >> 2) * 64 + bj) * 4 + (ns & 3))) << 12) + soff,
               Stream[ns & 1] + sdst);
    }
    const unsigned short* As = Fixed + (s & 3) * 4096;    // A = X_i rows
    const unsigned short* Bs = Stream[s & 1];             // B = Z_j cols
    bf16x8 b0 = *(const bf16x8*)&Bs[(C0 + fcol) * 32 + fro];
    bf16x8 b1 = *(const bf16x8*)&Bs[(C0 + 16 + fcol) * 32 + fro];
#pragma unroll
    for (int rt = 0; rt < 4; ++rt) {
      bf16x8 a = *(const bf16x8*)&As[(R0 + rt * 16 + fcol) * 32 + fro];
      acc[rt][0] = __builtin_amdgcn_mfma_f32_16x16x32_bf16(a, b0, acc[rt][0], 0, 0, 0);
      acc[rt][1] = __builtin_amdgcn_mfma_f32_16x16x32_bf16(a, b1, acc[rt][1], 0, 0, 0);
    }
    if ((s & 3) == 3) {
#pragma unroll
      for (int rt = 0; rt < 4; ++rt)
#pragma unroll
        for (int ct = 0; ct < 2; ++ct)
#pragma unroll
          for (int q = 0; q < 4; ++q) {
            m[rt][ct][q] = fmaxf(m[rt][ct][q], acc[rt][ct][q]);
            acc[rt][ct][q] = 0.f;
          }
    }
    __syncthreads();
  }

  // ---- epilogue: v = ((mI + mJT)/2 + 1)/2, upper store, mirror via Tb ----
  const float beta = betap[0];
  const bool bp = (beta != 1.0f);
  float vv[4][2][4];
#pragma unroll
  for (int rt = 0; rt < 4; ++rt)
#pragma unroll
    for (int ct = 0; ct < 2; ++ct) {
      unsigned int w0 = Park[(((rt * 2 + ct) * 2 + 0) * 512) + t];
      unsigned int w1 = Park[(((rt * 2 + ct) * 2 + 1) * 512) + t];
      float mi[4] = {bf2f((unsigned short)(w0 & 0xFFFF)),
                     bf2f((unsigned short)(w0 >> 16)),
                     bf2f((unsigned short)(w1 & 0xFFFF)),
                     bf2f((unsigned short)(w1 >> 16))};
#pragma unroll
      for (int q = 0; q < 4; ++q) {
        int r = R0 + rt * 16 + fkq * 4 + q;
        int c = C0 + ct * 16 + fcol;
        float v = 0.25f * (mi[q] + m[rt][ct][q]) + 0.5f;
        if (bp) v = powf(v, beta);
        out[(size_t)(bi * BT + r) * N_NODES + (size_t)(bj * BT + c)] = v;
        vv[rt][ct][q] = v;
      }
    }
  __syncthreads();   // all Park reads done before Tb overwrite

#pragma unroll
  for (int rt = 0; rt < 4; ++rt)
#pragma unroll
    for (int ct = 0; ct < 2; ++ct)
#pragma unroll
      for (int q = 0; q < 4; ++q) {
        int r = R0 + rt * 16 + fkq * 4 + q;
        int c = C0 + ct * 16 + fcol;
        Tb[c * 128 + (r ^ ((c & 15) << 1))] = f2bf(vv[rt][ct][q]);   // v^T
      }
  __syncthreads();

  if (bi != bj) {
#pragma unroll
    for (int it = 0; it < 16; ++it) {
      int row = it * 8 + w;
      unsigned int tw = *(const unsigned int*)&Tb[row * 128 + ((lane * 2) ^ ((row & 15) << 1))];
      float2 o;
      o.x = bf2f((unsigned short)(tw & 0xFFFF));
      o.y = bf2f((unsigned short)(tw >> 16));
      *(float2*)&out[(size_t)(bj * BT + row) * N_NODES + (size_t)(bi * BT + lane * 2)] = o;
    }
  }
}

extern "C" void kernel_launch(void* const* d_in, const int* in_sizes, int n_in,
                              void* d_out, int out_size, void* d_ws, size_t ws_size,
                              hipStream_t stream) {
  const float* X = (const float*)d_in[0];
  const float* W = (const float*)d_in[1];
  const float* Z = (const float*)d_in[2];
  const float* beta = (const float*)d_in[3];
  float* out = (float*)d_out;
  char* ws = (char*)d_ws;

  unsigned short* Xs = (unsigned short*)ws;                // 2 MiB K-sliced bf16
  unsigned short* Zs = (unsigned short*)(ws + (2u << 20)); // 8 MiB K-sliced bf16

  hipLaunchKernelGGL(xw_kernel, dim3(N_NODES / 32), dim3(512), 0, stream, X, W, Xs);
  hipLaunchKernelGGL(znorm_kernel, dim3(N_HEADS * N_NODES / 4), dim3(256), 0, stream, Z, Zs);
  hipLaunchKernelGGL(affinity_kernel, dim3(NPAIR), dim3(512), 0, stream, Xs, Zs, beta, out);
}